// Round 9
// baseline (106.802 us; speedup 1.0000x reference)
//
#include <hip/hip_runtime.h>
#include <hip/hip_bf16.h>

typedef __attribute__((ext_vector_type(8))) short short8;
typedef __attribute__((ext_vector_type(4))) float f32x4;

static __device__ __forceinline__ float lrelu(float a) {
    return a > 0.0f ? a : 0.2f * a;
}
// fp32 -> bf16 bits, round-to-nearest-even
static __device__ __forceinline__ unsigned f2bf(float f) {
    unsigned u = __float_as_uint(f);
    return (u + 0x7fffu + ((u >> 16) & 1u)) >> 16;
}
static __device__ __forceinline__ float bf2f(unsigned b) {
    return __uint_as_float(b << 16);
}
static __device__ __forceinline__ unsigned pack2(float a, float b) {
    return f2bf(a) | (f2bf(b) << 16);
}

// ---------------- KA: fused zero(cnt) + build Bb (independent block ranges) ----------------
// blocks [0, nZero): zero cnt (int4). blocks [nZero, nZero+36): build Bb
// (144 x 128 bf16) = [W rows | ws | wd], packed 2 bf16/uint.
__global__ __launch_bounds__(256) void zero_prep_kernel(
    const float* __restrict__ W, const float* __restrict__ att,
    unsigned* __restrict__ Bbu, int4* __restrict__ cnt4, int n4, int nZero)
{
    if ((int)blockIdx.x < nZero) {
        int i = blockIdx.x * 256 + threadIdx.x;
        if (i < n4) cnt4[i] = make_int4(0, 0, 0, 0);
        return;
    }
    int i = (blockIdx.x - nZero) * 256 + threadIdx.x;
    if (i < 8192) {
        Bbu[i] = pack2(W[2 * i], W[2 * i + 1]);
    } else if (i < 9216) {
        int e = (i - 8192) * 2;      // element in 16x128 extra rows
        int r2 = e >> 7;             // 0..15
        int k = e & 127;             // even
        int h = r2 & 7, sel = r2 >> 3;
        const float* ap = att + h * 32 + sel * 16;
        float v0 = 0.0f, v1 = 0.0f;
        for (int c = 0; c < 16; c++) {
            float a = ap[c];
            v0 = fmaf(a, W[(h * 16 + c) * 128 + k], v0);
            v1 = fmaf(a, W[(h * 16 + c) * 128 + k + 1], v1);
        }
        Bbu[i] = pack2(v0, v1);
    }
}

// ---------------- KB: fused MFMA GEMM + in-degree histogram ----------------
// blocks [0, nGemm): xtb = bf16(x @ Bb^T), s,d from extra cols.
// blocks [nGemm, ...): count_deg atomics (independent of gemm output).
__global__ __launch_bounds__(256) void gemm_count_kernel(
    const float* __restrict__ x, const uint4* __restrict__ Bb4,
    unsigned short* __restrict__ xtb16, float* __restrict__ s,
    float* __restrict__ d, int n, int nGemm,
    const int* __restrict__ ei, int* __restrict__ cnt, int E)
{
    __shared__ uint4 BbL[2304];   // 144 rows x 16 chunks of 16B, swizzled
    const int t = threadIdx.x;
    if ((int)blockIdx.x >= nGemm) {
        int e = ((int)blockIdx.x - nGemm) * 256 + t;
        if (e < E) atomicAdd(&cnt[ei[E + e]], 1);
        return;
    }
    for (int c = t; c < 2304; c += 256) {
        int j = c >> 4, kc = c & 15;
        BbL[(j << 4) | (kc ^ (j & 15))] = Bb4[c];
    }
    __syncthreads();

    const int lane = t & 63;
    const int wid = t >> 6;
    const int l15 = lane & 15, lhi = lane >> 4;
    const int row0 = blockIdx.x * 64 + wid * 16;
    const int arow = min(row0 + l15, n - 1);
    const float4* xv = (const float4*)(x + (size_t)arow * 128);

    float4 A0[4], A1[4];
    #pragma unroll
    for (int ks = 0; ks < 4; ks++) {
        A0[ks] = xv[ks * 8 + lhi * 2];
        A1[ks] = xv[ks * 8 + lhi * 2 + 1];
    }

    f32x4 acc[9];
    #pragma unroll
    for (int ct = 0; ct < 9; ct++) acc[ct] = (f32x4){0.f, 0.f, 0.f, 0.f};

    #pragma unroll
    for (int ks = 0; ks < 4; ks++) {
        union { unsigned u[4]; short8 v; } af;
        af.u[0] = pack2(A0[ks].x, A0[ks].y);
        af.u[1] = pack2(A0[ks].z, A0[ks].w);
        af.u[2] = pack2(A1[ks].x, A1[ks].y);
        af.u[3] = pack2(A1[ks].z, A1[ks].w);
        const int kc = ks * 4 + lhi;
        #pragma unroll
        for (int ct = 0; ct < 9; ct++) {
            const int j = ct * 16 + l15;
            union { uint4 q; short8 v; } bfr;
            bfr.q = BbL[(j << 4) | (kc ^ (j & 15))];
            acc[ct] = __builtin_amdgcn_mfma_f32_16x16x32_bf16(af.v, bfr.v, acc[ct], 0, 0, 0);
        }
    }

    // epilogue: D col = lane&15, row = (lane>>4)*4 + reg
    #pragma unroll
    for (int r = 0; r < 4; r++) {
        const int row = row0 + lhi * 4 + r;
        if (row < n) {
            #pragma unroll
            for (int ct = 0; ct < 8; ct++)
                xtb16[(size_t)row * 128 + ct * 16 + l15] =
                    (unsigned short)f2bf(acc[ct][r]);
            const float v = acc[8][r];
            if (l15 < 8) s[row * 8 + l15] = v;
            else         d[row * 8 + (l15 - 8)] = v;
        }
    }
}

// ---------------- KD: single-block full scan (replaces reduce+scanb+bscan) ----------------
// 1024 threads; thread t owns CONTIGUOUS int4 chunk [t*nc, t*nc+nc). 13
// independent int4 loads per thread (L2-hot), block-wide Hillis-Steele over
// per-thread sums, then int4 writes of offsets + cursor-zero of cnt.
__global__ __launch_bounds__(1024) void scan_all_kernel(
    int* __restrict__ cnt, int* __restrict__ offsets, int n)
{
    const int t = threadIdx.x;
    const int n4 = (n + 3) >> 2;
    const int nc = (n4 + 1023) >> 10;      // int4 chunks per thread (<=16 for n<=65536)
    const int base = t * nc;
    const int own = min(nc, max(0, n4 - base));
    int4 v[16];
    int tot = 0;
    #pragma unroll
    for (int j = 0; j < 16; j++) {
        if (j < own) {
            v[j] = ((const int4*)cnt)[base + j];
            tot += v[j].x + v[j].y + v[j].z + v[j].w;
        }
    }
    __shared__ int lds[1024];
    lds[t] = tot;
    __syncthreads();
    for (int off = 1; off < 1024; off <<= 1) {
        int u = 0;
        if (t >= off) u = lds[t - off];
        __syncthreads();
        lds[t] += u;
        __syncthreads();
    }
    int run = lds[t] - tot;                // exclusive prefix of this thread's chunk
    #pragma unroll
    for (int j = 0; j < 16; j++) {
        if (j < own) {
            const int4 c = v[j];
            int4 o;
            o.x = run;
            o.y = run + c.x;
            o.z = run + c.x + c.y;
            o.w = run + c.x + c.y + c.z;
            run += c.x + c.y + c.z + c.w;
            ((int4*)offsets)[base + j] = o;
            ((int4*)cnt)[base + j] = make_int4(0, 0, 0, 0);   // becomes scatter cursor
        }
    }
    if (t == 1023) offsets[n] = lds[1023]; // total = E (pad counts are zero)
}

// ---------------- KE: scatter edge sources into CSR ----------------
__global__ void scatter_edges_kernel(
    const int* __restrict__ ei, const int* __restrict__ offsets,
    int* __restrict__ cursor, int* __restrict__ srcs, int E)
{
    int e = blockIdx.x * 256 + threadIdx.x;
    if (e < E) {
        int tgt = ei[E + e];
        int pos = offsets[tgt] + atomicAdd(&cursor[tgt], 1);
        srcs[pos] = ei[e];
    }
}

// ---------------- KF: fused softmax+aggregate, 4-wide 3-stage pipeline ----------------
__global__ __launch_bounds__(256) void aggregate_kernel(
    const unsigned* __restrict__ xtb, const float* __restrict__ s,
    const float* __restrict__ d, const int* __restrict__ offsets,
    const int* __restrict__ srcs, const float* __restrict__ bias,
    float* __restrict__ out, int n)
{
    const int wid = (blockIdx.x * 256 + threadIdx.x) >> 6;   // one wave per node
    const int lane = threadIdx.x & 63;
    if (wid >= n) return;
    const int node = wid;
    const int off = offsets[node];
    const int deg = offsets[node + 1] - off;
    const int hB = lane >> 3;                // lane owns cols 2*lane, 2*lane+1
    const float dB = d[node * 8 + hB];
    const float2 bv = ((const float2*)bias)[lane];

    // self-loop loads issue first (overlap pipeline fill)
    const float svn = s[node * 8 + hB];
    const unsigned un = xtb[(size_t)node * 64 + lane];

    // pipeline fill: idx batches A=[0,4), B=[4,8); data for batch A
    int ia0 = (0 < deg) ? srcs[off + 0] : node;
    int ia1 = (1 < deg) ? srcs[off + 1] : node;
    int ia2 = (2 < deg) ? srcs[off + 2] : node;
    int ia3 = (3 < deg) ? srcs[off + 3] : node;
    int ib0 = (4 < deg) ? srcs[off + 4] : node;
    int ib1 = (5 < deg) ? srcs[off + 5] : node;
    int ib2 = (6 < deg) ? srcs[off + 6] : node;
    int ib3 = (7 < deg) ? srcs[off + 7] : node;
    float sa0 = s[ia0 * 8 + hB], sa1 = s[ia1 * 8 + hB];
    float sa2 = s[ia2 * 8 + hB], sa3 = s[ia3 * 8 + hB];
    unsigned ua0 = xtb[(size_t)ia0 * 64 + lane];
    unsigned ua1 = xtb[(size_t)ia1 * 64 + lane];
    unsigned ua2 = xtb[(size_t)ia2 * 64 + lane];
    unsigned ua3 = xtb[(size_t)ia3 * 64 + lane];

    // self-loop contribution
    const float w_self = __expf(lrelu(svn + dB));
    float wsum = w_self;
    float accx = w_self * bf2f(un & 0xffffu);
    float accy = w_self * bf2f(un >> 16);

    for (int e = 0; e < deg; e += 4) {
        const int ic0 = (e + 8 < deg) ? srcs[off + e + 8] : node;
        const int ic1 = (e + 9 < deg) ? srcs[off + e + 9] : node;
        const int ic2 = (e + 10 < deg) ? srcs[off + e + 10] : node;
        const int ic3 = (e + 11 < deg) ? srcs[off + e + 11] : node;
        const float sb0 = s[ib0 * 8 + hB], sb1 = s[ib1 * 8 + hB];
        const float sb2 = s[ib2 * 8 + hB], sb3 = s[ib3 * 8 + hB];
        const unsigned ub0 = xtb[(size_t)ib0 * 64 + lane];
        const unsigned ub1 = xtb[(size_t)ib1 * 64 + lane];
        const unsigned ub2 = xtb[(size_t)ib2 * 64 + lane];
        const unsigned ub3 = xtb[(size_t)ib3 * 64 + lane];
        const float w0 = (e + 0 < deg) ? __expf(lrelu(sa0 + dB)) : 0.0f;
        const float w1 = (e + 1 < deg) ? __expf(lrelu(sa1 + dB)) : 0.0f;
        const float w2 = (e + 2 < deg) ? __expf(lrelu(sa2 + dB)) : 0.0f;
        const float w3 = (e + 3 < deg) ? __expf(lrelu(sa3 + dB)) : 0.0f;
        wsum += (w0 + w1) + (w2 + w3);
        accx = fmaf(w0, bf2f(ua0 & 0xffffu), accx);
        accy = fmaf(w0, bf2f(ua0 >> 16), accy);
        accx = fmaf(w1, bf2f(ua1 & 0xffffu), accx);
        accy = fmaf(w1, bf2f(ua1 >> 16), accy);
        accx = fmaf(w2, bf2f(ua2 & 0xffffu), accx);
        accy = fmaf(w2, bf2f(ua2 >> 16), accy);
        accx = fmaf(w3, bf2f(ua3 & 0xffffu), accx);
        accy = fmaf(w3, bf2f(ua3 >> 16), accy);
        sa0 = sb0; sa1 = sb1; sa2 = sb2; sa3 = sb3;
        ua0 = ub0; ua1 = ub1; ua2 = ub2; ua3 = ub3;
        ib0 = ic0; ib1 = ic1; ib2 = ic2; ib3 = ic3;
    }
    const float inv = 1.0f / wsum;
    ((float2*)out)[(size_t)node * 64 + lane] =
        make_float2(fmaf(accx, inv, bv.x), fmaf(accy, inv, bv.y));
}

extern "C" void kernel_launch(void* const* d_in, const int* in_sizes, int n_in,
                              void* d_out, int out_size, void* d_ws, size_t ws_size,
                              hipStream_t stream)
{
    const float* x    = (const float*)d_in[0];
    const int*   ei   = (const int*)d_in[1];
    const float* W    = (const float*)d_in[2];
    const float* att  = (const float*)d_in[3];
    const float* bias = (const float*)d_in[4];
    float* out = (float*)d_out;

    const int n = in_sizes[0] / 128;
    const int E = in_sizes[1] / 2;

    const size_t offs_pad = ((size_t)n + 4) & ~(size_t)3;
    const size_t cnt_pad  = ((size_t)n + 3) & ~(size_t)3;
    const size_t need_bytes =
        (size_t)n * 64 * sizeof(unsigned) +
        (size_t)n * 16 * sizeof(float) +
        (offs_pad + cnt_pad + (size_t)E + 9216) * sizeof(int);
    if (ws_size < need_bytes) return;   // clean failure, never OOB-write
    if (n > 65536) return;              // scan_all_kernel chunk bound (n=50000 here)

    unsigned* xtb = (unsigned*)d_ws;                // n*64 uints
    float* s  = (float*)(xtb + (size_t)n * 64);     // n*8
    float* d  = s + (size_t)n * 8;                  // n*8
    int* offsets = (int*)(d + (size_t)n * 8);       // n+1 (padded)
    int* cnt     = offsets + offs_pad;              // n (padded), counts then cursor
    int* srcs    = cnt + cnt_pad;                   // E
    unsigned* Bbu = (unsigned*)(srcs + E);          // 9216

    const int n4 = (int)(cnt_pad / 4);
    const int nZero = (n4 + 255) / 256;
    const int nGemm = (n + 63) / 64;
    const int nCount = (E + 255) / 256;

    zero_prep_kernel<<<dim3(nZero + 36), dim3(256), 0, stream>>>(
        W, att, Bbu, (int4*)cnt, n4, nZero);
    gemm_count_kernel<<<dim3(nGemm + nCount), dim3(256), 0, stream>>>(
        x, (const uint4*)Bbu, (unsigned short*)xtb, s, d, n, nGemm, ei, cnt, E);
    scan_all_kernel<<<dim3(1), dim3(1024), 0, stream>>>(cnt, offsets, n);
    scatter_edges_kernel<<<dim3(nCount), dim3(256), 0, stream>>>(ei, offsets, cnt, srcs, E);
    aggregate_kernel<<<dim3((n + 3) / 4), dim3(256), 0, stream>>>(
        xtb, s, d, offsets, srcs, bias, out, n);
}